// Round 7
// baseline (129.307 us; speedup 1.0000x reference)
//
#include <hip/hip_runtime.h>
#include <hip/hip_bf16.h>
#include <float.h>

// Problem constants
#define BATCH 8
#define CHN   64
#define HW    56
#define PIX   3136          // 56*56
#define LDB   72            // band LDS stride in bf16 elems (144 B, 16-B aligned)

typedef __bf16 bf16x8 __attribute__((ext_vector_type(8)));
typedef float  f32x4  __attribute__((ext_vector_type(4)));

static __device__ __forceinline__ unsigned short f2bf(float f) {
    unsigned int u = __float_as_uint(f);
    u += 0x7fffu + ((u >> 16) & 1u);          // round-to-nearest-even
    return (unsigned short)(u >> 16);
}

// ---------------------------------------------------------------------------
// Stage 1 (blocks 0..97): invnorm[b,p] = 1/sqrt(sum_c x^2) (fp64) + x->bf16
// transpose xT[b][p][c].  Block 98: pack W -> bf16 wbf[o][tap][c] so the mega
// kernel can load A-fragments with b128s.
// ---------------------------------------------------------------------------
__global__ __launch_bounds__(256) void norm_kernel(const float* __restrict__ x,
                                                   const float* __restrict__ w,
                                                   double* __restrict__ invn,
                                                   unsigned short* __restrict__ xT,
                                                   unsigned short* __restrict__ wbf) {
    if (blockIdx.x == 98) {                       // W prep: 64*9*64 = 36864 elems
        for (int l = threadIdx.x; l < 36864; l += 256) {
            int otap = l >> 6, c = l & 63;        // dst = (o*9+tap)*64 + c
            int o = otap / 9, tap = otap - o * 9;
            wbf[l] = f2bf(w[(o * 64 + c) * 9 + tap]);
        }
        return;
    }
    int idx = blockIdx.x * 256 + threadIdx.x;     // (b,p), 25088 = 98*256
    int b = idx / PIX, p = idx - b * PIX;
    const float* xb = x + (size_t)b * CHN * PIX + p;
    double s = 0.0;
    unsigned int pack[32];
    #pragma unroll
    for (int c2 = 0; c2 < 32; c2++) {
        float v0 = xb[(2 * c2) * PIX];
        float v1 = xb[(2 * c2 + 1) * PIX];
        s += (double)v0 * (double)v0 + (double)v1 * (double)v1;
        pack[c2] = (unsigned int)f2bf(v0) | ((unsigned int)f2bf(v1) << 16);
    }
    uint4* dst = (uint4*)(xT + (size_t)idx * CHN);
    #pragma unroll
    for (int i = 0; i < 8; i++) dst[i] = ((uint4*)pack)[i];
    invn[idx] = 1.0 / sqrt(s);
}

// ---------------------------------------------------------------------------
// Mega kernel: per (b, image row r) does dots -> select -> MFMA gather-conv.
// LDS map (56704 B total, phase-overlapped):
//   tile  float [9600]  @ [0, 38400)       phase A only (dead after)
//   band  ushort[21600] @ [0, 43200)       written phase B, read phase C
//   keys  double[1400]  @ [43200, 54400)   written phase A end, read phase B
//   qtab  int   [576]   @ [54400, 56704)   written phase B, read phase C
// Phase A: 2 chunks of 32 channels, fp32 tile, fp64 products (cvt exact) in
// channel order 0..63 — bit-identical keys to the R5-verified select.
// Phase B: t<56 = 9-rank stable select + index sort -> qtab; t in[56,64) zero
// qtab tail; t>=64 stage the bf16 band (concurrent, disjoint LDS).
// Phase C: R5-verified indexed-ds_read_b128 MFMA loop, direct out write.
// ---------------------------------------------------------------------------
__global__ __launch_bounds__(256) void mega_kernel(const float* __restrict__ x,
                                                   const unsigned short* __restrict__ xT,
                                                   const unsigned short* __restrict__ wbf,
                                                   const double* __restrict__ invn,
                                                   float* __restrict__ out) {
    const int b = blockIdx.y;
    const int r = blockIdx.x;
    __shared__ __align__(16) char smem[56704];
    float*          tile = (float*)smem;
    unsigned short* band = (unsigned short*)smem;
    double*         keys = (double*)(smem + 43200);
    int*            qtab = (int*)(smem + 54400);
    const int t = threadIdx.x;

    // ---- A-fragments (registers; b128 loads from packed wbf) ----
    const int wv = t >> 6, ln = t & 63;
    const int mrow = ln & 15, kq = ln >> 4;
    const int o = wv * 16 + mrow;
    bf16x8 afr[9][2];
    #pragma unroll
    for (int tap = 0; tap < 9; tap++) {
        #pragma unroll
        for (int half = 0; half < 2; half++) {
            afr[tap][half] = *(const bf16x8*)(wbf + (size_t)(o * 9 + tap) * 64 + half * 32 + kq * 8);
        }
    }

    // ---- Phase A: fp64 dots (verified logic; 2x32-ch chunks) ----
    const int g = t / 56, j = t - g * 56;         // t<224 active
    const bool active = (t < 224);
    int off[7]; bool sval[7];
    #pragma unroll
    for (int u = 0; u < 7; u++) {
        int s = g * 7 + u;
        bool in_range = (s < 25);
        int dr = (in_range ? s : 0) / 5 - 2;
        int dc = (in_range ? s : 0) % 5 - 2;
        off[u] = dr * 60 + dc;
        int qi = r + dr, qj = j + dc;
        sval[u] = in_range && qi >= 0 && qi < HW && qj >= 0 && qj < HW;
    }
    double acc[7];
    #pragma unroll
    for (int u = 0; u < 7; u++) acc[u] = 0.0;

    const float* xb = x + (size_t)b * CHN * PIX;
    for (int cc = 0; cc < CHN; cc += 32) {
        __syncthreads();
        for (int l = t; l < 9600; l += 256) {     // stage [32ch][5 rows][60 cols]
            int cl = l / 300; int rem = l - cl * 300;
            int lr = rem / 60; int col = rem - lr * 60 - 2;
            int row = r - 2 + lr;
            float v = 0.0f;
            if (row >= 0 && row < HW && col >= 0 && col < HW)
                v = xb[(size_t)(cc + cl) * PIX + row * HW + col];
            tile[l] = v;
        }
        __syncthreads();
        if (active) {
            #pragma unroll
            for (int cl = 0; cl < 32; cl++) {
                const float* tr = &tile[cl * 300 + 2 * 60 + (j + 2)];
                double ctr = (double)tr[0];
                #pragma unroll
                for (int u = 0; u < 7; u++) acc[u] += ctr * (double)tr[off[u]];
            }
        }
    }
    if (active) {                                  // finalize keys (invn + validity)
        const double* inb = invn + (size_t)b * PIX;
        #pragma unroll
        for (int u = 0; u < 7; u++) {
            int s = g * 7 + u;
            if (s < 25) {
                int dr = s / 5 - 2, dc = s % 5 - 2;
                keys[j * 25 + s] = sval[u] ? acc[u] * inb[(r + dr) * HW + (j + dc)] : DBL_MAX;
            }
        }
    }
    __syncthreads();                               // keys visible; tile dead

    // ---- Phase B: select (t<56) || zero qtab tail || stage band (t>=64) ----
    if (t < 56) {
        const int jj = t;
        double k2[25];
        #pragma unroll
        for (int s = 0; s < 25; s++) k2[s] = keys[jj * 25 + s];
        unsigned int used = 0;
        int bq[9];
        #pragma unroll
        for (int rr = 0; rr < 9; rr++) {
            double best = DBL_MAX; int bs = 0;
            #pragma unroll
            for (int s = 0; s < 25; s++) {
                bool ok = (((used >> s) & 1u) == 0u) && (k2[s] < best);
                if (ok) { best = k2[s]; bs = s; }
            }
            used |= (1u << bs);
            bq[rr] = (r + bs / 5 - 2) * HW + (jj + bs % 5 - 2);
        }
        #pragma unroll
        for (int a = 0; a < 8; a++) {
            #pragma unroll
            for (int c2 = 0; c2 < 8 - a; c2++) {
                int u = bq[c2], v = bq[c2 + 1];
                bq[c2] = u < v ? u : v; bq[c2 + 1] = u < v ? v : u;
            }
        }
        #pragma unroll
        for (int k = 0; k < 9; k++) {
            int q = bq[k], qi = q / HW, qj = q - qi * HW;
            qtab[k * 64 + jj] = ((qi - r + 2) * 60 + qj + 2) * LDB;
        }
    } else if (t < 64) {
        #pragma unroll
        for (int k = 0; k < 9; k++) qtab[k * 64 + t] = 0;   // tail (p>=56) safe dummy
    } else {
        for (int l = t - 64; l < 2400; l += 192) {          // band: 300 locals x 8 ch-chunks
            int local = l >> 3, ch8 = l & 7;
            int lr = local / 60, col = local - lr * 60 - 2;
            int row = r - 2 + lr;
            uint4 v = {0, 0, 0, 0};
            if (row >= 0 && row < HW && col >= 0 && col < HW)
                v = *(const uint4*)(xT + ((size_t)b * PIX + row * HW + col) * CHN + ch8 * 8);
            *(uint4*)(&band[local * LDB + ch8 * 8]) = v;
        }
    }
    __syncthreads();

    // ---- Phase C: MFMA gather-conv (verified R5) ----
    f32x4 oacc[4] = {{0,0,0,0},{0,0,0,0},{0,0,0,0},{0,0,0,0}};
    #pragma unroll
    for (int tap = 0; tap < 9; tap++) {
        #pragma unroll
        for (int nt = 0; nt < 4; nt++) {
            int q = qtab[tap * 64 + nt * 16 + mrow];
            const unsigned short* bp = &band[q + kq * 8];
            bf16x8 b0 = *(const bf16x8*)bp;
            bf16x8 b1 = *(const bf16x8*)(bp + 32);
            oacc[nt] = __builtin_amdgcn_mfma_f32_16x16x32_bf16(afr[tap][0], b0, oacc[nt], 0, 0, 0);
            oacc[nt] = __builtin_amdgcn_mfma_f32_16x16x32_bf16(afr[tap][1], b1, oacc[nt], 0, 0, 0);
        }
    }
    // C/D: col = lane&15 = p-within-tile, row = kq*4+rg = o-within-strip
    float* ob = out + ((size_t)b * 64 + wv * 16 + kq * 4) * PIX + r * HW;
    #pragma unroll
    for (int nt = 0; nt < 4; nt++) {
        int p = nt * 16 + mrow;
        if (p < HW) {
            #pragma unroll
            for (int rg = 0; rg < 4; rg++) ob[(size_t)rg * PIX + p] = oacc[nt][rg];
        }
    }
}

// ---------------------------------------------------------------------------
// Workspace layout (total ~3.5 MB):
//   invn : 25088 * 8      =   200,704 B @ 0
//   wbf  : 64*9*64 * 2    =    73,728 B @ 200,704
//   xT   : 8*3136*64 * 2  = 3,211,264 B @ 274,432
// ---------------------------------------------------------------------------
extern "C" void kernel_launch(void* const* d_in, const int* in_sizes, int n_in,
                              void* d_out, int out_size, void* d_ws, size_t ws_size,
                              hipStream_t stream) {
    const float* x = (const float*)d_in[0];
    const float* w = (const float*)d_in[1];
    float* out = (float*)d_out;
    char* ws = (char*)d_ws;
    double*         invn = (double*)ws;
    unsigned short* wbf  = (unsigned short*)(ws + 200704);
    unsigned short* xT   = (unsigned short*)(ws + 274432);

    norm_kernel<<<99, 256, 0, stream>>>(x, w, invn, xT, wbf);
    mega_kernel<<<dim3(56, 8), 256, 0, stream>>>(x, xT, wbf, invn, out);
}

// Round 8
// 123.792 us; speedup vs baseline: 1.0446x; 1.0446x over previous
//
#include <hip/hip_runtime.h>
#include <hip/hip_bf16.h>
#include <float.h>

// Problem constants
#define BATCH 8
#define CHN   64
#define HW    56
#define PIX   3136          // 56*56
#define LDB   72            // band LDS stride in bf16 elems (144 B, 16-B aligned)
#define DSTR  16            // dots row stride (doubles): slots 0..14 used

typedef __bf16 bf16x8 __attribute__((ext_vector_type(8)));
typedef float  f32x4  __attribute__((ext_vector_type(4)));

static __device__ __forceinline__ unsigned short f2bf(float f) {
    unsigned int u = __float_as_uint(f);
    u += 0x7fffu + ((u >> 16) & 1u);          // round-to-nearest-even
    return (unsigned short)(u >> 16);
}
static __device__ __forceinline__ int clampq(int q) {
    return q < 0 ? 0 : (q > PIX - 2 ? PIX - 2 : q);
}

// ---------------------------------------------------------------------------
// Stage 1: dots[b][p][s] for s=0..14 (window rows dr=-2..0), fp64, sequential
// over c — bit-identical numerators to the R1-verified select. Rows dr=+1,+2
// are exact mirrors (IEEE mul commutes): dots[p][s] == dots[p+off][24-s],
// resolved at read time in stage 2. Thread = (pixel pair j,j+1; source row
// sg=0..2). 4 aligned float2 loads per channel, no LDS, no barriers.
// Also emits invn[p] = 1.0/sqrt(dots center) (sg==2) and packs wbf (r==56).
// ---------------------------------------------------------------------------
__global__ __launch_bounds__(128) void dots_kernel(const float* __restrict__ x,
                                                   const float* __restrict__ w,
                                                   double* __restrict__ dots,
                                                   double* __restrict__ invn,
                                                   unsigned short* __restrict__ wbf) {
    const int b = blockIdx.y;
    const int r = blockIdx.x;
    if (r == HW) {                                // wbf pack tail: 64*9*64 elems
        if (b == 0) {
            for (int l = threadIdx.x; l < 36864; l += 128) {
                int otap = l >> 6, c = l & 63;    // dst = (o*9+tap)*64 + c
                int o = otap / 9, tap = otap - o * 9;
                wbf[l] = f2bf(w[(o * CHN + c) * 9 + tap]);
            }
        }
        return;
    }
    const int t = threadIdx.x;
    if (t >= 84) return;
    const int sg = t / 28;                        // source row dr = sg-2 (0..2)
    const int j2 = t - sg * 28;
    const int j  = 2 * j2;                        // pixels j, j+1 of row r
    const int p  = r * HW + j;
    const int row = r + sg - 2;
    const int q0 = clampq(row * HW + j - 2);      // span cols j-2..j+3 (even)
    const int q1 = clampq(row * HW + j);
    const int q2 = clampq(row * HW + j + 2);

    const float* xb = x + (size_t)b * CHN * PIX;
    double a0[5] = {0, 0, 0, 0, 0};               // px j  : dc = -2..2
    double a1[5] = {0, 0, 0, 0, 0};               // px j+1: dc = -2..2
    #pragma unroll 4
    for (int c = 0; c < CHN; c++) {
        const float* xc = xb + (size_t)c * PIX;
        float2 ct = *(const float2*)(xc + p);
        float2 n0 = *(const float2*)(xc + q0);
        float2 n1 = *(const float2*)(xc + q1);
        float2 n2 = *(const float2*)(xc + q2);
        double d0 = (double)ct.x, d1 = (double)ct.y;
        double v0 = (double)n0.x, v1 = (double)n0.y;
        double v2 = (double)n1.x, v3 = (double)n1.y;
        double v4 = (double)n2.x, v5 = (double)n2.y;
        a0[0] += d0 * v0; a0[1] += d0 * v1; a0[2] += d0 * v2;
        a0[3] += d0 * v3; a0[4] += d0 * v4;
        a1[0] += d1 * v1; a1[1] += d1 * v2; a1[2] += d1 * v3;
        a1[3] += d1 * v4; a1[4] += d1 * v5;
    }
    double* dp = dots + ((size_t)b * PIX + p) * DSTR + sg * 5;
    #pragma unroll
    for (int k = 0; k < 5; k++) dp[k] = a0[k];
    #pragma unroll
    for (int k = 0; k < 5; k++) dp[DSTR + k] = a1[k];
    if (sg == 2) {                                // center = s=12 (dr=0,dc=0)
        invn[(size_t)b * PIX + p]     = 1.0 / sqrt(a0[2]);
        invn[(size_t)b * PIX + p + 1] = 1.0 / sqrt(a1[2]);
    }
}

// ---------------------------------------------------------------------------
// Stage 2 (fused select + gather-conv), per (b, image row r).
// Wave 0 (t<56): build 25 keys from global dots (s<15 direct, s>=15 mirror
// dots[q][24-s]) * invn[q], DBL_MAX for invalid — bit-identical keys to the
// R1-verified kernel; 9-rank stable select + ascending index sort -> qtab.
// t in [56,64): zero qtab tail. t>=64: stage bf16 band from x (zero-padded).
// Then the R5-verified indexed-ds_read_b128 MFMA loop, direct out write.
// LDS: band 43200 B + qtab 2304 B = 45.5 KB -> 3 blocks/CU.
// ---------------------------------------------------------------------------
__global__ __launch_bounds__(256) void fused_kernel(const float* __restrict__ x,
                                                    const double* __restrict__ dots,
                                                    const double* __restrict__ invn,
                                                    const unsigned short* __restrict__ wbf,
                                                    float* __restrict__ out) {
    const int b = blockIdx.y;
    const int r = blockIdx.x;
    __shared__ unsigned short band[300 * LDB];
    __shared__ int qtab[9 * 64];
    const int t = threadIdx.x;

    // A-fragments (registers; b128 loads from packed wbf)
    const int wv = t >> 6, ln = t & 63;
    const int mrow = ln & 15, kq = ln >> 4;
    const int o = wv * 16 + mrow;
    bf16x8 afr[9][2];
    #pragma unroll
    for (int tap = 0; tap < 9; tap++) {
        #pragma unroll
        for (int half = 0; half < 2; half++) {
            afr[tap][half] = *(const bf16x8*)(wbf + (size_t)(o * 9 + tap) * 64 + half * 32 + kq * 8);
        }
    }

    if (t < 56) {
        const int jj = t;
        const double* dp  = dots + ((size_t)b * PIX + r * HW + jj) * DSTR;
        const double* inb = invn + (size_t)b * PIX;
        double k2[25];
        #pragma unroll
        for (int s = 0; s < 25; s++) {
            int dr = s / 5 - 2, dc = s % 5 - 2;
            int qi = r + dr, qj = jj + dc;
            bool valid = qi >= 0 && qi < HW && qj >= 0 && qj < HW;
            int q = qi * HW + qj;
            double raw;
            if (s < 15) raw = dp[s];
            else        raw = valid ? dots[((size_t)b * PIX + q) * DSTR + (24 - s)] : 0.0;
            k2[s] = valid ? raw * inb[q] : DBL_MAX;
        }
        unsigned int used = 0;
        int bq[9];
        #pragma unroll
        for (int rr = 0; rr < 9; rr++) {
            double best = DBL_MAX; int bs = 0;
            #pragma unroll
            for (int s = 0; s < 25; s++) {
                bool ok = (((used >> s) & 1u) == 0u) && (k2[s] < best);
                if (ok) { best = k2[s]; bs = s; }
            }
            used |= (1u << bs);
            bq[rr] = (r + bs / 5 - 2) * HW + (jj + bs % 5 - 2);
        }
        #pragma unroll
        for (int a = 0; a < 8; a++) {
            #pragma unroll
            for (int c2 = 0; c2 < 8 - a; c2++) {
                int u = bq[c2], v = bq[c2 + 1];
                bq[c2] = u < v ? u : v; bq[c2 + 1] = u < v ? v : u;
            }
        }
        #pragma unroll
        for (int k = 0; k < 9; k++) {
            int q = bq[k], qi = q / HW, qj = q - qi * HW;
            qtab[k * 64 + jj] = ((qi - r + 2) * 60 + qj + 2) * LDB;
        }
    } else if (t < 64) {
        #pragma unroll
        for (int k = 0; k < 9; k++) qtab[k * 64 + t] = 0;   // tail dummy
    } else {
        // band: 300 locals x 32 channel-pairs; lanes sweep locals (coalesced)
        const float* xb = x + (size_t)b * CHN * PIX;
        for (int l = t - 64; l < 9600; l += 192) {
            int cpair = l / 300;
            int local = l - cpair * 300;
            int lr = local / 60, col = local - lr * 60 - 2;
            int row = r - 2 + lr;
            unsigned int pk = 0;
            if (row >= 0 && row < HW && col >= 0 && col < HW) {
                int q = row * HW + col;
                float v0 = xb[(size_t)(2 * cpair) * PIX + q];
                float v1 = xb[(size_t)(2 * cpair + 1) * PIX + q];
                pk = (unsigned int)f2bf(v0) | ((unsigned int)f2bf(v1) << 16);
            }
            *(unsigned int*)&band[local * LDB + 2 * cpair] = pk;
        }
    }
    __syncthreads();

    // MFMA gather-conv (verified R5/R7)
    f32x4 oacc[4] = {{0,0,0,0},{0,0,0,0},{0,0,0,0},{0,0,0,0}};
    #pragma unroll
    for (int tap = 0; tap < 9; tap++) {
        #pragma unroll
        for (int nt = 0; nt < 4; nt++) {
            int q = qtab[tap * 64 + nt * 16 + mrow];
            const unsigned short* bp = &band[q + kq * 8];
            bf16x8 b0 = *(const bf16x8*)bp;
            bf16x8 b1 = *(const bf16x8*)(bp + 32);
            oacc[nt] = __builtin_amdgcn_mfma_f32_16x16x32_bf16(afr[tap][0], b0, oacc[nt], 0, 0, 0);
            oacc[nt] = __builtin_amdgcn_mfma_f32_16x16x32_bf16(afr[tap][1], b1, oacc[nt], 0, 0, 0);
        }
    }
    // C/D: col = lane&15 = p-within-tile, row = kq*4+rg = o-within-strip
    float* ob = out + ((size_t)b * 64 + wv * 16 + kq * 4) * PIX + r * HW;
    #pragma unroll
    for (int nt = 0; nt < 4; nt++) {
        int p = nt * 16 + mrow;
        if (p < HW) {
            #pragma unroll
            for (int rg = 0; rg < 4; rg++) ob[(size_t)rg * PIX + p] = oacc[nt][rg];
        }
    }
}

// ---------------------------------------------------------------------------
// Workspace layout (total ~3.5 MB):
//   dots : 25088 * 16 * 8 = 3,211,264 B @ 0
//   invn : 25088 * 8      =   200,704 B @ 3,211,264
//   wbf  : 64*9*64 * 2    =    73,728 B @ 3,411,968
// ---------------------------------------------------------------------------
extern "C" void kernel_launch(void* const* d_in, const int* in_sizes, int n_in,
                              void* d_out, int out_size, void* d_ws, size_t ws_size,
                              hipStream_t stream) {
    const float* x = (const float*)d_in[0];
    const float* w = (const float*)d_in[1];
    float* out = (float*)d_out;
    char* ws = (char*)d_ws;
    double*         dots = (double*)ws;
    double*         invn = (double*)(ws + 3211264);
    unsigned short* wbf  = (unsigned short*)(ws + 3411968);

    dots_kernel<<<dim3(57, 8), 128, 0, stream>>>(x, w, dots, invn, wbf);
    fused_kernel<<<dim3(56, 8), 256, 0, stream>>>(x, dots, invn, wbf, out);
}

// Round 9
// 97.796 us; speedup vs baseline: 1.3222x; 1.2658x over previous
//
#include <hip/hip_runtime.h>
#include <hip/hip_bf16.h>
#include <float.h>

// Problem constants
#define BATCH 8
#define CHN   64
#define HW    56
#define PIX   3136          // 56*56
#define LDB   72            // band LDS stride in bf16 elems (144 B, 16-B aligned)
#define DSTR  16            // dots row stride (doubles): slots 0..14 used

typedef __bf16 bf16x8 __attribute__((ext_vector_type(8)));
typedef float  f32x4  __attribute__((ext_vector_type(4)));

static __device__ __forceinline__ unsigned short f2bf(float f) {
    unsigned int u = __float_as_uint(f);
    u += 0x7fffu + ((u >> 16) & 1u);          // round-to-nearest-even
    return (unsigned short)(u >> 16);
}

// ---------------------------------------------------------------------------
// Stage 1: dots[b][p][s], s=0..14 (window rows dr<=0), fp64 sequential over
// c=0..63 — bit-identical to the R1-verified keys. Rows dr=+1,+2 are exact
// mirrors (IEEE mul commutes): read as dots[q][24-s] in stage 2.
// Thread = (b, r, s, j): one slot of one pixel. 376,320 threads (5880 waves,
// ~23/CU) — fixes R8's 3.5-waves/CU latency starvation. Lanes sweep j
// (contiguous), so center loads broadcast and neighbor loads coalesce.
// Invalid slots: clamped address, garbage value, masked in stage 2.
// s==12 (center) also emits invn = 1/sqrt(dot). Tail blocks pack wbf.
// ---------------------------------------------------------------------------
__global__ __launch_bounds__(256) void dots_kernel(const float* __restrict__ x,
                                                   const float* __restrict__ w,
                                                   double* __restrict__ dots,
                                                   double* __restrict__ invn,
                                                   unsigned short* __restrict__ wbf) {
    int idx = blockIdx.x * 256 + threadIdx.x;
    if (idx >= 376320) {                          // 16 tail blocks: pack wbf
        int wi = idx - 376320;                    // 4096 threads x 9 elems
        #pragma unroll
        for (int k = 0; k < 9; k++) {
            int l = wi + k * 4096;                // l = (o*9+tap)*64 + c
            int otap = l >> 6, c = l & 63;
            int o = otap / 9, tap = otap - o * 9;
            wbf[l] = f2bf(w[(o * CHN + c) * 9 + tap]);
        }
        return;
    }
    const int b  = idx / 47040;
    int rem      = idx - b * 47040;
    const int r  = rem / 840;
    rem          = rem - r * 840;
    const int s  = rem / 56;                      // 0..14
    const int j  = rem - s * 56;
    const int p  = r * HW + j;
    const int dr = s / 5 - 2, dc = s % 5 - 2;
    const int qi = r + dr, qj = j + dc;
    int q = qi * HW + qj;
    q = q < 0 ? 0 : (q >= PIX ? PIX - 1 : q);     // clamp (invalid -> masked later)

    const float* xp = x + (size_t)b * CHN * PIX + p;
    const float* xq = x + (size_t)b * CHN * PIX + q;
    double acc = 0.0;
    #pragma unroll 8
    for (int c = 0; c < CHN; c++) {
        acc += (double)xp[c * PIX] * (double)xq[c * PIX];
    }
    dots[((size_t)b * PIX + p) * DSTR + s] = acc;
    if (s == 12) invn[(size_t)b * PIX + p] = 1.0 / sqrt(acc);
}

// ---------------------------------------------------------------------------
// Stage 2 (fused select + gather-conv), per (b, image row r).  [R8-verified]
// Wave 0 (t<56): build 25 keys from global dots (s<15 direct, s>=15 mirror
// dots[q][24-s]) * invn[q], DBL_MAX for invalid; 9-rank stable select +
// ascending index sort -> qtab. t in [56,64): zero qtab tail. t>=64: stage
// bf16 band from x. Then indexed-ds_read_b128 MFMA loop, direct out write.
// LDS: band 43200 B + qtab 2304 B = 45.5 KB -> 3 blocks/CU.
// ---------------------------------------------------------------------------
__global__ __launch_bounds__(256) void fused_kernel(const float* __restrict__ x,
                                                    const double* __restrict__ dots,
                                                    const double* __restrict__ invn,
                                                    const unsigned short* __restrict__ wbf,
                                                    float* __restrict__ out) {
    const int b = blockIdx.y;
    const int r = blockIdx.x;
    __shared__ unsigned short band[300 * LDB];
    __shared__ int qtab[9 * 64];
    const int t = threadIdx.x;

    // A-fragments (registers; b128 loads from packed wbf)
    const int wv = t >> 6, ln = t & 63;
    const int mrow = ln & 15, kq = ln >> 4;
    const int o = wv * 16 + mrow;
    bf16x8 afr[9][2];
    #pragma unroll
    for (int tap = 0; tap < 9; tap++) {
        #pragma unroll
        for (int half = 0; half < 2; half++) {
            afr[tap][half] = *(const bf16x8*)(wbf + (size_t)(o * 9 + tap) * 64 + half * 32 + kq * 8);
        }
    }

    if (t < 56) {
        const int jj = t;
        const double* dp  = dots + ((size_t)b * PIX + r * HW + jj) * DSTR;
        const double* inb = invn + (size_t)b * PIX;
        double k2[25];
        #pragma unroll
        for (int s = 0; s < 25; s++) {
            int dr = s / 5 - 2, dc = s % 5 - 2;
            int qi = r + dr, qj = jj + dc;
            bool valid = qi >= 0 && qi < HW && qj >= 0 && qj < HW;
            int q = qi * HW + qj;
            double raw;
            if (s < 15) raw = dp[s];
            else        raw = valid ? dots[((size_t)b * PIX + q) * DSTR + (24 - s)] : 0.0;
            k2[s] = valid ? raw * inb[q] : DBL_MAX;
        }
        unsigned int used = 0;
        int bq[9];
        #pragma unroll
        for (int rr = 0; rr < 9; rr++) {
            double best = DBL_MAX; int bs = 0;
            #pragma unroll
            for (int s = 0; s < 25; s++) {
                bool ok = (((used >> s) & 1u) == 0u) && (k2[s] < best);
                if (ok) { best = k2[s]; bs = s; }
            }
            used |= (1u << bs);
            bq[rr] = (r + bs / 5 - 2) * HW + (jj + bs % 5 - 2);
        }
        #pragma unroll
        for (int a = 0; a < 8; a++) {
            #pragma unroll
            for (int c2 = 0; c2 < 8 - a; c2++) {
                int u = bq[c2], v = bq[c2 + 1];
                bq[c2] = u < v ? u : v; bq[c2 + 1] = u < v ? v : u;
            }
        }
        #pragma unroll
        for (int k = 0; k < 9; k++) {
            int q = bq[k], qi = q / HW, qj = q - qi * HW;
            qtab[k * 64 + jj] = ((qi - r + 2) * 60 + qj + 2) * LDB;
        }
    } else if (t < 64) {
        #pragma unroll
        for (int k = 0; k < 9; k++) qtab[k * 64 + t] = 0;   // tail dummy
    } else {
        // band: 300 locals x 32 channel-pairs; lanes sweep locals (coalesced)
        const float* xb = x + (size_t)b * CHN * PIX;
        for (int l = t - 64; l < 9600; l += 192) {
            int cpair = l / 300;
            int local = l - cpair * 300;
            int lr = local / 60, col = local - lr * 60 - 2;
            int row = r - 2 + lr;
            unsigned int pk = 0;
            if (row >= 0 && row < HW && col >= 0 && col < HW) {
                int q = row * HW + col;
                float v0 = xb[(size_t)(2 * cpair) * PIX + q];
                float v1 = xb[(size_t)(2 * cpair + 1) * PIX + q];
                pk = (unsigned int)f2bf(v0) | ((unsigned int)f2bf(v1) << 16);
            }
            *(unsigned int*)&band[local * LDB + 2 * cpair] = pk;
        }
    }
    __syncthreads();

    // MFMA gather-conv (verified R5/R7/R8)
    f32x4 oacc[4] = {{0,0,0,0},{0,0,0,0},{0,0,0,0},{0,0,0,0}};
    #pragma unroll
    for (int tap = 0; tap < 9; tap++) {
        #pragma unroll
        for (int nt = 0; nt < 4; nt++) {
            int q = qtab[tap * 64 + nt * 16 + mrow];
            const unsigned short* bp = &band[q + kq * 8];
            bf16x8 b0 = *(const bf16x8*)bp;
            bf16x8 b1 = *(const bf16x8*)(bp + 32);
            oacc[nt] = __builtin_amdgcn_mfma_f32_16x16x32_bf16(afr[tap][0], b0, oacc[nt], 0, 0, 0);
            oacc[nt] = __builtin_amdgcn_mfma_f32_16x16x32_bf16(afr[tap][1], b1, oacc[nt], 0, 0, 0);
        }
    }
    // C/D: col = lane&15 = p-within-tile, row = kq*4+rg = o-within-strip
    float* ob = out + ((size_t)b * 64 + wv * 16 + kq * 4) * PIX + r * HW;
    #pragma unroll
    for (int nt = 0; nt < 4; nt++) {
        int p = nt * 16 + mrow;
        if (p < HW) {
            #pragma unroll
            for (int rg = 0; rg < 4; rg++) ob[(size_t)rg * PIX + p] = oacc[nt][rg];
        }
    }
}

// ---------------------------------------------------------------------------
// Workspace layout (total ~3.5 MB):
//   dots : 25088 * 16 * 8 = 3,211,264 B @ 0
//   invn : 25088 * 8      =   200,704 B @ 3,211,264
//   wbf  : 64*9*64 * 2    =    73,728 B @ 3,411,968
// ---------------------------------------------------------------------------
extern "C" void kernel_launch(void* const* d_in, const int* in_sizes, int n_in,
                              void* d_out, int out_size, void* d_ws, size_t ws_size,
                              hipStream_t stream) {
    const float* x = (const float*)d_in[0];
    const float* w = (const float*)d_in[1];
    float* out = (float*)d_out;
    char* ws = (char*)d_ws;
    double*         dots = (double*)ws;
    double*         invn = (double*)(ws + 3211264);
    unsigned short* wbf  = (unsigned short*)(ws + 3411968);

    // 1470 blocks cover (b,r,s,j); 16 tail blocks pack wbf
    dots_kernel<<<1486, 256, 0, stream>>>(x, w, dots, invn, wbf);
    fused_kernel<<<dim3(56, 8), 256, 0, stream>>>(x, dots, invn, wbf, out);
}